// Round 3
// baseline (1629.484 us; speedup 1.0000x reference)
//
#include <hip/hip_runtime.h>
#include <math.h>

#define NB 32
#define NS 4096
#define ND 768
#define NH 1024
#define NTOK (NB*NS)
#define NKC (ND/32)   // 24 k-chunks

typedef __bf16 bf16_t;
typedef __bf16 bf16x8 __attribute__((ext_vector_type(8)));
typedef float  f32x4  __attribute__((ext_vector_type(4)));

// ---------------------------------------------------------------------------
// Kernel A: LayerNorm statistics. One wave per token, 3x float4 per lane.
// ---------------------------------------------------------------------------
__global__ __launch_bounds__(256) void k_lnstats(
    const float* __restrict__ emb, const float* __restrict__ attn,
    float* __restrict__ mu_o, float* __restrict__ rs_o)
{
    const int token = blockIdx.x * 4 + (threadIdx.x >> 6);
    const int lane  = threadIdx.x & 63;
    const float am  = attn[token];
    const float* row = emb + (size_t)token * ND;

    float e[12];
    {
        const float4 v0 = *(const float4*)(row + lane * 4);
        const float4 v1 = *(const float4*)(row + 256 + lane * 4);
        const float4 v2 = *(const float4*)(row + 512 + lane * 4);
        e[0]=v0.x; e[1]=v0.y; e[2]=v0.z; e[3]=v0.w;
        e[4]=v1.x; e[5]=v1.y; e[6]=v1.z; e[7]=v1.w;
        e[8]=v2.x; e[9]=v2.y; e[10]=v2.z; e[11]=v2.w;
    }
    float s = 0.f;
#pragma unroll
    for (int j = 0; j < 12; j++) { e[j] *= am; s += e[j]; }
#pragma unroll
    for (int m = 32; m; m >>= 1) s += __shfl_xor(s, m, 64);
    const float mu = s * (1.0f / ND);

    float v = 0.f;
#pragma unroll
    for (int j = 0; j < 12; j++) { float d = e[j] - mu; v += d * d; }
#pragma unroll
    for (int m = 32; m; m >>= 1) v += __shfl_xor(v, m, 64);
    v *= (1.0f / ND);

    if (lane == 0) {
        mu_o[token] = mu;
        rs_o[token] = (float)(1.0 / sqrt((double)v + 1e-5));
    }
}

// ---------------------------------------------------------------------------
// Kernel P: split w1 into bf16 hi/lo, re-blocked to the exact LDS image
// (XOR swizzle pre-applied). Block index: [(c*64 + h16)*512 + lane*8].
// ---------------------------------------------------------------------------
__global__ __launch_bounds__(256) void k_wprep(
    const float* __restrict__ w1, bf16_t* __restrict__ whB, bf16_t* __restrict__ wlB)
{
    const int t   = blockIdx.x * 256 + threadIdx.x;   // [0, 24*64*64)
    const int ln  = t & 63;
    const int h16 = (t >> 6) & 63;
    const int c   = t >> 12;
    const int row = h16 * 16 + (ln >> 2);
    const int k0  = c * 32 + 8 * ((ln & 3) ^ (ln >> 4));

    const float4 a = *(const float4*)(w1 + (size_t)row * ND + k0);
    const float4 b = *(const float4*)(w1 + (size_t)row * ND + k0 + 4);
    const float vv[8] = {a.x,a.y,a.z,a.w,b.x,b.y,b.z,b.w};
    bf16x8 hi, lo;
#pragma unroll
    for (int j = 0; j < 8; j++) {
        const bf16_t hj = (bf16_t)vv[j];
        hi[j] = hj;
        lo[j] = (bf16_t)(vv[j] - (float)hj);
    }
    const size_t o = (size_t)t * 8;
    *(bf16x8*)(whB + o) = hi;
    *(bf16x8*)(wlB + o) = lo;
}

// ---------------------------------------------------------------------------
// Kernel B: fused LN + MLP scorer via bf16x3-split MFMA (16x16x32).
// v3 (resubmit; round-2 bench died to infra with no kernel signal).
// TM 64 -> 256. Theory: W (hi+lo, 4.5 MB > 4 MiB XCD L2) was re-streamed
// from LLC by every 64-token block: 6.1 GB/dispatch (~8 TB/s cache stream
// at 857 us) -- the unmeasured bandwidth wall. 256 tokens/block cuts W
// traffic 4x (1.53 GB); emb re-reads unchanged (LLC-resident).
//   - 512 threads / 8 waves; wave grid = 4 token-quarters x 2 H-halves.
//   - per wave: 4 tt x 8 ht tiles, acc = 128 regs; per-kc MFMA phase
//     ~3.7k cyc/SIMD >> DMA (32 KB) + X-load latency -> fully hidden.
//   - Both W and X double-buffered in LDS; ONE barrier per k-chunk.
// LDS: Wh/Wl 2x16K each + Xh/Xl 2x16K each + sred 2K = 130 KB -> 1 block/CU
// (8 waves = 2/SIMD, same occupancy as before; VGPR capped at 256 by
// __launch_bounds__(512,2)).
// ---------------------------------------------------------------------------
#define TM 256
#define KC 32

__global__ __launch_bounds__(512, 2) void k_scorer(
    const float* __restrict__ emb, const float* __restrict__ attn,
    const float* __restrict__ ln_g, const float* __restrict__ ln_b,
    const bf16_t* __restrict__ whB, const bf16_t* __restrict__ wlB,
    const float* __restrict__ b1, const float* __restrict__ w2,
    const float* __restrict__ b2v,
    const float* __restrict__ mu_a, const float* __restrict__ rs_a,
    float* __restrict__ scores)
{
    __shared__ __align__(16) bf16_t sWh[2][256*32];
    __shared__ __align__(16) bf16_t sWl[2][256*32];
    __shared__ __align__(16) bf16_t sXh[2][256*32];
    __shared__ __align__(16) bf16_t sXl[2][256*32];
    __shared__ float sred[2][256];

    const int tid    = threadIdx.x;
    const int lane   = tid & 63;
    const int wv     = tid >> 6;      // 0..7
    const int wt     = wv >> 1;       // 0..3 : token quarter (64 tokens)
    const int wh     = wv & 1;        // 0..1 : H half of the 256-row pass tile
    const int token0 = blockIdx.x * TM;

    // ---- X staging role: 2 threads per token row, 16 elems each ----
    const int xt  = tid >> 1;         // 0..255
    const int xp  = tid & 1;
    const int xm  = (xt >> 2) & 3;
    const int sl0 = (xp * 2 + 0) ^ xm;   // logical k-part for physical slot 2xp
    const int sl1 = (xp * 2 + 1) ^ xm;   // logical k-part for physical slot 2xp+1
    const float x_mu = mu_a[token0 + xt];
    const float x_rs = rs_a[token0 + xt];
    const float x_at = attn[token0 + xt];
    const float* embrow = emb + (size_t)(token0 + xt) * ND;

    // ---- compute role ----
    const int cn  = lane & 15;
    const int cq  = lane >> 4;
    const int fsw = (cq ^ (cn >> 2)) << 3;

    f32x4 acc[4][8];                  // [tt][ht] -> 128 regs
    float spart[16];
#pragma unroll
    for (int i = 0; i < 16; i++) spart[i] = 0.f;

    // X prefetch registers (emb only; ln_g/ln_b are 3 KB -> L1-resident,
    // loaded directly in storeX)
    float4 xe0, xe1, xe2, xe3;
    int xkc = 0;

    auto loadX = [&](int c) {
        xkc = c * KC;
        xe0 = *(const float4*)(embrow + xkc + 8 * sl0);
        xe1 = *(const float4*)(embrow + xkc + 8 * sl0 + 4);
        xe2 = *(const float4*)(embrow + xkc + 8 * sl1);
        xe3 = *(const float4*)(embrow + xkc + 8 * sl1 + 4);
    };
    auto storeX = [&](int buf) {
        const float4 g0 = *(const float4*)(ln_g + xkc + 8 * sl0);
        const float4 g1 = *(const float4*)(ln_g + xkc + 8 * sl0 + 4);
        const float4 c0 = *(const float4*)(ln_b + xkc + 8 * sl0);
        const float4 c1 = *(const float4*)(ln_b + xkc + 8 * sl0 + 4);
        const float4 g2 = *(const float4*)(ln_g + xkc + 8 * sl1);
        const float4 g3 = *(const float4*)(ln_g + xkc + 8 * sl1 + 4);
        const float4 c2 = *(const float4*)(ln_b + xkc + 8 * sl1);
        const float4 c3 = *(const float4*)(ln_b + xkc + 8 * sl1 + 4);
        {
            const float ev[8] = {xe0.x,xe0.y,xe0.z,xe0.w,xe1.x,xe1.y,xe1.z,xe1.w};
            const float gv[8] = {g0.x,g0.y,g0.z,g0.w,g1.x,g1.y,g1.z,g1.w};
            const float cv[8] = {c0.x,c0.y,c0.z,c0.w,c1.x,c1.y,c1.z,c1.w};
            bf16x8 hi, lo;
#pragma unroll
            for (int j = 0; j < 8; j++) {
                const float x = (ev[j] * x_at - x_mu) * x_rs * gv[j] + cv[j];
                const bf16_t hb = (bf16_t)x;
                hi[j] = hb;
                lo[j] = (bf16_t)(x - (float)hb);
            }
            *(bf16x8*)&sXh[buf][xt*32 + (xp*2 + 0)*8] = hi;
            *(bf16x8*)&sXl[buf][xt*32 + (xp*2 + 0)*8] = lo;
        }
        {
            const float ev[8] = {xe2.x,xe2.y,xe2.z,xe2.w,xe3.x,xe3.y,xe3.z,xe3.w};
            const float gv[8] = {g2.x,g2.y,g2.z,g2.w,g3.x,g3.y,g3.z,g3.w};
            const float cv[8] = {c2.x,c2.y,c2.z,c2.w,c3.x,c3.y,c3.z,c3.w};
            bf16x8 hi, lo;
#pragma unroll
            for (int j = 0; j < 8; j++) {
                const float x = (ev[j] * x_at - x_mu) * x_rs * gv[j] + cv[j];
                const bf16_t hb = (bf16_t)x;
                hi[j] = hb;
                lo[j] = (bf16_t)(x - (float)hb);
            }
            *(bf16x8*)&sXh[buf][xt*32 + (xp*2 + 1)*8] = hi;
            *(bf16x8*)&sXl[buf][xt*32 + (xp*2 + 1)*8] = lo;
        }
    };
    auto issueW = [&](int hq, int c, int buf) {
        const int grp4 = wv >> 1;                 // 0..3: four 16-row groups
        const bf16_t* gsrc = (wv & 1) ? wlB : whB;
        bf16_t* lbase = (wv & 1) ? &sWl[buf][0] : &sWh[buf][0];
        const size_t blk = ((size_t)(c * 64 + hq * 16 + grp4 * 4)) * 512 + lane * 8;
#pragma unroll
        for (int i = 0; i < 4; i++)
            __builtin_amdgcn_global_load_lds(
                (const __attribute__((address_space(1))) void*)(gsrc + blk + (size_t)i * 512),
                (__attribute__((address_space(3))) void*)(lbase + (grp4*64 + i*16)*32),
                16, 0, 0);
    };

    // ---- prologue: stage chunk (hq=0, c=0) into buffer 0 ----
    loadX(0);
    issueW(0, 0, 0);
    storeX(0);
    __syncthreads();   // drains W vmcnt + X lgkm; chunk 0 ready

    int cur = 0;
    for (int hq = 0; hq < 4; hq++) {
#pragma unroll
        for (int tt = 0; tt < 4; tt++)
#pragma unroll
            for (int ht = 0; ht < 8; ht++) acc[tt][ht] = (f32x4){0.f, 0.f, 0.f, 0.f};

        for (int c = 0; c < 24; c++) {
            const bool lastiter = (hq == 3) && (c == 23);
            // ---- prefetch chunk t+1: X -> regs, W -> LDS buf^1 ----
            if (!lastiter) {
                const int nhq = (c == 23) ? hq + 1 : hq;
                const int nc  = (c == 23) ? 0 : c + 1;
                loadX(nc);
                issueW(nhq, nc, cur ^ 1);
            }
            // ---- MFMA phase on chunk t (buffer cur): 4 tt x 8 ht x 3 ----
            bf16x8 ah[4], al[4];
#pragma unroll
            for (int tt = 0; tt < 4; tt++) {
                const int off = (wt*64 + tt*16 + cn)*32 + fsw;
                ah[tt] = *(const bf16x8*)&sXh[cur][off];
                al[tt] = *(const bf16x8*)&sXl[cur][off];
            }
#pragma unroll
            for (int ht = 0; ht < 8; ht++) {
                const int off = (wh*128 + ht*16 + cn)*32 + fsw;
                const bf16x8 bh = *(const bf16x8*)&sWh[cur][off];
                const bf16x8 bl = *(const bf16x8*)&sWl[cur][off];
#pragma unroll
                for (int tt = 0; tt < 4; tt++) {
                    acc[tt][ht] = __builtin_amdgcn_mfma_f32_16x16x32_bf16(ah[tt], bh, acc[tt][ht], 0, 0, 0);
                    acc[tt][ht] = __builtin_amdgcn_mfma_f32_16x16x32_bf16(al[tt], bh, acc[tt][ht], 0, 0, 0);
                    acc[tt][ht] = __builtin_amdgcn_mfma_f32_16x16x32_bf16(ah[tt], bl, acc[tt][ht], 0, 0, 0);
                }
            }
            // ---- finish staging X(t+1) into the alternate buffer ----
            if (!lastiter) storeX(cur ^ 1);
            __syncthreads();   // one barrier per kc: drains DMA vmcnt (landed
                               // under the ~3.7k-cyc MFMA phase) + X ds_writes
            cur ^= 1;
        }
        // ---- epilogue for this quarter: bias + exact gelu + w2 reduce ----
#pragma unroll
        for (int ht = 0; ht < 8; ht++) {
            const int hg = hq*256 + wh*128 + ht*16 + cn;
            const float b1v = b1[hg];
            const float w2v = w2[hg];
#pragma unroll
            for (int tt = 0; tt < 4; tt++)
#pragma unroll
                for (int r = 0; r < 4; r++) {
                    const float pre = acc[tt][ht][r] + b1v;
                    const float ge  = 0.5f * pre * (1.0f + erff(pre * 0.70710678118654752f));
                    spart[tt*4 + r] += ge * w2v;
                }
        }
    }
#pragma unroll
    for (int i = 0; i < 16; i++) {
        float s = spart[i];
        s += __shfl_xor(s, 1, 64);
        s += __shfl_xor(s, 2, 64);
        s += __shfl_xor(s, 4, 64);
        s += __shfl_xor(s, 8, 64);
        spart[i] = s;
    }
    if (cn == 0) {
#pragma unroll
        for (int tt = 0; tt < 4; tt++)
#pragma unroll
            for (int r = 0; r < 4; r++)
                sred[wh][wt*64 + tt*16 + cq*4 + r] = spart[tt*4 + r];
    }
    __syncthreads();
    if (tid < TM) {
        scores[token0 + tid] = sred[0][tid] + sred[1][tid] + b2v[0];
    }
}

// ---------------------------------------------------------------------------
// Kernel TG: entmax1.5 tau (fp64 bisection) + Kumaraswamy gate, fused.
// One 1024-thread block per batch row. tau is block-uniform in registers.
// ---------------------------------------------------------------------------
static __device__ __forceinline__ double softplus_d(double x) {
    return (x > 30.0) ? x : log1p(exp(x));
}

__global__ __launch_bounds__(1024) void k_taugate(
    const float* __restrict__ scores, const float* __restrict__ attn,
    const float* __restrict__ u, float* __restrict__ out)
{
    const int b    = blockIdx.x;
    const int tid  = threadIdx.x;
    const int lane = tid & 63;
    const int wid  = tid >> 6;

    __shared__ double redd[2][16];
    __shared__ float  redf[16];
    __shared__ float  bcf;

    float vv[4], at[4], sm[4];
#pragma unroll
    for (int j = 0; j < 4; j++) {
        const int i = tid + 1024 * j;
        at[j] = attn[b * NS + i];
        const float s = scores[b * NS + i];
        sm[j] = (at[j] == 0.0f) ? -1e9f : s;
        vv[j] = sm[j] * 0.5f;
    }

    float mx = fmaxf(fmaxf(vv[0], vv[1]), fmaxf(vv[2], vv[3]));
#pragma unroll
    for (int m = 32; m; m >>= 1) mx = fmaxf(mx, __shfl_xor(mx, m, 64));
    if (lane == 0) redf[wid] = mx;
    __syncthreads();
    if (tid == 0) {
        float t = redf[0];
        for (int i = 1; i < 16; i++) t = fmaxf(t, redf[i]);
        bcf = t;
    }
    __syncthreads();
    const double mxd = (double)bcf;

    double d[4];
#pragma unroll
    for (int j = 0; j < 4; j++) d[j] = (double)vv[j] - mxd;

    double lo = -1.0, hi = 0.0;
    for (int it = 0; it < 44; it++) {
        const double mid = 0.5 * (lo + hi);
        double s = 0.0;
#pragma unroll
        for (int j = 0; j < 4; j++) {
            const double t = d[j] - mid;
            if (t > 0.0) s += t * t;
        }
#pragma unroll
        for (int m = 32; m; m >>= 1) s += __shfl_xor(s, m, 64);
        const int p = it & 1;
        if (lane == 0) redd[p][wid] = s;
        __syncthreads();
        double tot = 0.0;
#pragma unroll
        for (int i = 0; i < 16; i++) tot += redd[p][i];
        if (tot >= 1.0) lo = mid; else hi = mid;   // uniform across block
    }
    const double tau = lo;

    if (b == 0 && tid == 0) out[2 * NTOK] = 0.0f;  // reg

#pragma unroll
    for (int j = 0; j < 4; j++) {
        const int i = tid + 1024 * j;
        const double t  = d[j] - tau;
        const double zz = (t > 0.0) ? t * t : 0.0;
        const float  z  = (float)zz * at[j];

        const double eff  = (double)sm[j] + 2.0 * (2.0 * (double)z - 1.0);
        const double sp_p = softplus_d(eff)  + 1e-6;
        const double sp_n = softplus_d(-eff) + 1e-6;
        const double uc   = fmin(fmax((double)u[b * NS + i], 1e-6), 1.0 - 1e-6);
        const double xk   = pow(1.0 - pow(1.0 - uc, 1.0 / sp_n), 1.0 / sp_p);
        const double y    = -0.1 + 1.2 * xk;
        const double ycl  = fmin(fmax(y, 0.0), 1.0);
        float h = (ycl > 0.5) ? 1.0f : 0.0f;
        h *= at[j];
        const float g = (h - z) + z;

        out[b * NS + i]        = z;
        out[NTOK + b * NS + i] = g;
    }
}

// ---------------------------------------------------------------------------
extern "C" void kernel_launch(void* const* d_in, const int* in_sizes, int n_in,
                              void* d_out, int out_size, void* d_ws, size_t ws_size,
                              hipStream_t stream)
{
    const float* emb  = (const float*)d_in[0];
    const float* attn = (const float*)d_in[1];
    const float* u    = (const float*)d_in[2];
    const float* ln_g = (const float*)d_in[3];
    const float* ln_b = (const float*)d_in[4];
    const float* w1   = (const float*)d_in[5];
    const float* b1   = (const float*)d_in[6];
    const float* w2   = (const float*)d_in[7];
    const float* b2   = (const float*)d_in[8];
    float* out = (float*)d_out;

    float*  wsf    = (float*)d_ws;
    float*  scores = wsf;                       // NTOK
    float*  mu     = wsf + NTOK;                // NTOK
    float*  rs     = wsf + 2 * NTOK;            // NTOK
    bf16_t* w1hB   = (bf16_t*)(wsf + 3 * NTOK); // NH*ND bf16 (blocked)
    bf16_t* w1lB   = w1hB + (size_t)NH * ND;

    hipLaunchKernelGGL(k_lnstats, dim3(NTOK / 4), dim3(256), 0, stream,
                       emb, attn, mu, rs);
    hipLaunchKernelGGL(k_wprep, dim3((NKC * 64 * 64) / 256), dim3(256), 0, stream,
                       w1, w1hB, w1lB);
    hipLaunchKernelGGL(k_scorer, dim3(NTOK / TM), dim3(512), 0, stream,
                       emb, attn, ln_g, ln_b, w1hB, w1lB, b1, w2, b2, mu, rs, scores);
    hipLaunchKernelGGL(k_taugate, dim3(NB), dim3(1024), 0, stream,
                       scores, attn, u, out);
}

// Round 4
// 1288.673 us; speedup vs baseline: 1.2645x; 1.2645x over previous
//
#include <hip/hip_runtime.h>
#include <math.h>

#define NB 32
#define NS 4096
#define ND 768
#define NH 1024
#define NTOK (NB*NS)
#define NKC (ND/32)   // 24 k-chunks

typedef __bf16 bf16_t;
typedef __bf16 bf16x8 __attribute__((ext_vector_type(8)));
typedef float  f32x4  __attribute__((ext_vector_type(4)));

// ---------------------------------------------------------------------------
// Kernel A: LayerNorm statistics. One wave per token, 3x float4 per lane.
// ---------------------------------------------------------------------------
__global__ __launch_bounds__(256) void k_lnstats(
    const float* __restrict__ emb, const float* __restrict__ attn,
    float* __restrict__ mu_o, float* __restrict__ rs_o)
{
    const int token = blockIdx.x * 4 + (threadIdx.x >> 6);
    const int lane  = threadIdx.x & 63;
    const float am  = attn[token];
    const float* row = emb + (size_t)token * ND;

    float e[12];
    {
        const float4 v0 = *(const float4*)(row + lane * 4);
        const float4 v1 = *(const float4*)(row + 256 + lane * 4);
        const float4 v2 = *(const float4*)(row + 512 + lane * 4);
        e[0]=v0.x; e[1]=v0.y; e[2]=v0.z; e[3]=v0.w;
        e[4]=v1.x; e[5]=v1.y; e[6]=v1.z; e[7]=v1.w;
        e[8]=v2.x; e[9]=v2.y; e[10]=v2.z; e[11]=v2.w;
    }
    float s = 0.f;
#pragma unroll
    for (int j = 0; j < 12; j++) { e[j] *= am; s += e[j]; }
#pragma unroll
    for (int m = 32; m; m >>= 1) s += __shfl_xor(s, m, 64);
    const float mu = s * (1.0f / ND);

    float v = 0.f;
#pragma unroll
    for (int j = 0; j < 12; j++) { float d = e[j] - mu; v += d * d; }
#pragma unroll
    for (int m = 32; m; m >>= 1) v += __shfl_xor(v, m, 64);
    v *= (1.0f / ND);

    if (lane == 0) {
        mu_o[token] = mu;
        rs_o[token] = (float)(1.0 / sqrt((double)v + 1e-5));
    }
}

// ---------------------------------------------------------------------------
// Kernel P: split w1 into bf16 hi/lo, re-blocked to the exact LDS image
// (XOR swizzle pre-applied). Block index: [(c*64 + h16)*512 + lane*8].
// ---------------------------------------------------------------------------
__global__ __launch_bounds__(256) void k_wprep(
    const float* __restrict__ w1, bf16_t* __restrict__ whB, bf16_t* __restrict__ wlB)
{
    const int t   = blockIdx.x * 256 + threadIdx.x;   // [0, 24*64*64)
    const int ln  = t & 63;
    const int h16 = (t >> 6) & 63;
    const int c   = t >> 12;
    const int row = h16 * 16 + (ln >> 2);
    const int k0  = c * 32 + 8 * ((ln & 3) ^ (ln >> 4));

    const float4 a = *(const float4*)(w1 + (size_t)row * ND + k0);
    const float4 b = *(const float4*)(w1 + (size_t)row * ND + k0 + 4);
    const float vv[8] = {a.x,a.y,a.z,a.w,b.x,b.y,b.z,b.w};
    bf16x8 hi, lo;
#pragma unroll
    for (int j = 0; j < 8; j++) {
        const bf16_t hj = (bf16_t)vv[j];
        hi[j] = hj;
        lo[j] = (bf16_t)(vv[j] - (float)hj);
    }
    const size_t o = (size_t)t * 8;
    *(bf16x8*)(whB + o) = hi;
    *(bf16x8*)(wlB + o) = lo;
}

// ---------------------------------------------------------------------------
// Kernel B: fused LN + MLP scorer via bf16x3-split MFMA (16x16x32).
// v4: TM=128. Post-mortem of v3 (TM=256): acc[4][8]=128 unified regs
// overflowed the 256-reg budget -> ~3 KB/thread scratch (WRITE_SIZE 799 MB),
// kernel became spill-bound. v4 keeps the verified round-1 per-wave register
// profile (acc[4][4], 4-thread/row X staging) and halves the W stream
// relative to TM=64 via 1 block/CU x 32 KB W-DMA per chunk (was 2 x 32 KB):
//   - 512 threads / 8 waves; wave grid = 2 token-halves x 4 H-quarters.
//   - W + X double-buffered in LDS; ONE barrier per k-chunk; W DMA and
//     X register-prefetch for chunk t+1 issued before MFMA(t).
// LDS: Wh/Wl 2x16K each + Xh/Xl 2x8K each + sred 2K = 98 KB -> 1 block/CU
// (8 waves = 2/SIMD, occupancy unchanged vs rounds 0-1).
// ---------------------------------------------------------------------------
#define TM 128
#define KC 32

__global__ __launch_bounds__(512, 2) void k_scorer(
    const float* __restrict__ emb, const float* __restrict__ attn,
    const float* __restrict__ ln_g, const float* __restrict__ ln_b,
    const bf16_t* __restrict__ whB, const bf16_t* __restrict__ wlB,
    const float* __restrict__ b1, const float* __restrict__ w2,
    const float* __restrict__ b2v,
    const float* __restrict__ mu_a, const float* __restrict__ rs_a,
    float* __restrict__ scores)
{
    __shared__ __align__(16) bf16_t sWh[2][256*32];
    __shared__ __align__(16) bf16_t sWl[2][256*32];
    __shared__ __align__(16) bf16_t sXh[2][128*32];
    __shared__ __align__(16) bf16_t sXl[2][128*32];
    __shared__ float sred[4][128];

    const int tid    = threadIdx.x;
    const int lane   = tid & 63;
    const int wv     = tid >> 6;      // 0..7
    const int wt     = wv >> 2;       // 0..1 : token half (64 tokens)
    const int wh     = wv & 3;        // 0..3 : H quarter of the 256-row pass tile
    const int token0 = blockIdx.x * TM;

    // ---- X staging role: 4 threads per token row, 8 elems each ----
    const int xt  = tid >> 2;         // 0..127
    const int xp  = tid & 3;
    const int xk8 = 8 * (xp ^ ((xt >> 2) & 3));
    const float x_mu = mu_a[token0 + xt];
    const float x_rs = rs_a[token0 + xt];
    const float x_at = attn[token0 + xt];
    const float* embrow = emb + (size_t)(token0 + xt) * ND;

    // ---- compute role ----
    const int cn  = lane & 15;
    const int cq  = lane >> 4;
    const int fsw = (cq ^ (cn >> 2)) << 3;

    f32x4 acc[4][4];
    float spart[16];
#pragma unroll
    for (int i = 0; i < 16; i++) spart[i] = 0.f;

    // X prefetch registers (issue-early / use-late)
    float4 xe0, xe1;
    int xkc = 0;

    auto loadX = [&](int c) {
        xkc = c * KC;
        xe0 = *(const float4*)(embrow + xkc + xk8);
        xe1 = *(const float4*)(embrow + xkc + xk8 + 4);
    };
    auto storeX = [&](int buf) {
        const float4 g0 = *(const float4*)(ln_g + xkc + xk8);
        const float4 g1 = *(const float4*)(ln_g + xkc + xk8 + 4);
        const float4 c0 = *(const float4*)(ln_b + xkc + xk8);
        const float4 c1 = *(const float4*)(ln_b + xkc + xk8 + 4);
        const float ev[8] = {xe0.x,xe0.y,xe0.z,xe0.w,xe1.x,xe1.y,xe1.z,xe1.w};
        const float gv[8] = {g0.x,g0.y,g0.z,g0.w,g1.x,g1.y,g1.z,g1.w};
        const float cv[8] = {c0.x,c0.y,c0.z,c0.w,c1.x,c1.y,c1.z,c1.w};
        bf16x8 hi, lo;
#pragma unroll
        for (int j = 0; j < 8; j++) {
            const float x = (ev[j] * x_at - x_mu) * x_rs * gv[j] + cv[j];
            const bf16_t hb = (bf16_t)x;
            hi[j] = hb;
            lo[j] = (bf16_t)(x - (float)hb);
        }
        *(bf16x8*)&sXh[buf][xt*32 + xp*8] = hi;
        *(bf16x8*)&sXl[buf][xt*32 + xp*8] = lo;
    };
    auto issueW = [&](int hq, int c, int buf) {
        const int grp4 = wv >> 1;                 // 0..3: four 16-row groups
        const bf16_t* gsrc = (wv & 1) ? wlB : whB;
        bf16_t* lbase = (wv & 1) ? &sWl[buf][0] : &sWh[buf][0];
        const size_t blk = ((size_t)(c * 64 + hq * 16 + grp4 * 4)) * 512 + lane * 8;
#pragma unroll
        for (int i = 0; i < 4; i++)
            __builtin_amdgcn_global_load_lds(
                (const __attribute__((address_space(1))) void*)(gsrc + blk + (size_t)i * 512),
                (__attribute__((address_space(3))) void*)(lbase + (grp4*64 + i*16)*32),
                16, 0, 0);
    };

    // ---- prologue: stage chunk (hq=0, c=0) into buffer 0 ----
    loadX(0);
    issueW(0, 0, 0);
    storeX(0);
    __syncthreads();   // drains W vmcnt + X lgkm; chunk 0 ready

    int cur = 0;
    for (int hq = 0; hq < 4; hq++) {
#pragma unroll
        for (int tt = 0; tt < 4; tt++)
#pragma unroll
            for (int ht = 0; ht < 4; ht++) acc[tt][ht] = (f32x4){0.f, 0.f, 0.f, 0.f};

        for (int c = 0; c < 24; c++) {
            const bool lastiter = (hq == 3) && (c == 23);
            // ---- prefetch chunk t+1: X -> regs, W -> LDS buf^1 ----
            if (!lastiter) {
                const int nhq = (c == 23) ? hq + 1 : hq;
                const int nc  = (c == 23) ? 0 : c + 1;
                loadX(nc);
                issueW(nhq, nc, cur ^ 1);
            }
            // ---- MFMA phase on chunk t (buffer cur): 4 tt x 4 ht x 3 ----
            bf16x8 ah[4], al[4];
#pragma unroll
            for (int tt = 0; tt < 4; tt++) {
                const int off = (wt*64 + tt*16 + cn)*32 + fsw;
                ah[tt] = *(const bf16x8*)&sXh[cur][off];
                al[tt] = *(const bf16x8*)&sXl[cur][off];
            }
#pragma unroll
            for (int ht = 0; ht < 4; ht++) {
                const int off = (wh*64 + ht*16 + cn)*32 + fsw;
                const bf16x8 bh = *(const bf16x8*)&sWh[cur][off];
                const bf16x8 bl = *(const bf16x8*)&sWl[cur][off];
#pragma unroll
                for (int tt = 0; tt < 4; tt++) {
                    acc[tt][ht] = __builtin_amdgcn_mfma_f32_16x16x32_bf16(ah[tt], bh, acc[tt][ht], 0, 0, 0);
                    acc[tt][ht] = __builtin_amdgcn_mfma_f32_16x16x32_bf16(al[tt], bh, acc[tt][ht], 0, 0, 0);
                    acc[tt][ht] = __builtin_amdgcn_mfma_f32_16x16x32_bf16(ah[tt], bl, acc[tt][ht], 0, 0, 0);
                }
            }
            // ---- finish staging X(t+1) into the alternate buffer ----
            if (!lastiter) storeX(cur ^ 1);
            __syncthreads();   // one barrier per kc: drains DMA vmcnt (landed
                               // under the MFMA phase) + X ds_writes
            cur ^= 1;
        }
        // ---- epilogue for this quarter: bias + exact gelu + w2 reduce ----
#pragma unroll
        for (int ht = 0; ht < 4; ht++) {
            const int hg = hq*256 + wh*64 + ht*16 + cn;
            const float b1v = b1[hg];
            const float w2v = w2[hg];
#pragma unroll
            for (int tt = 0; tt < 4; tt++)
#pragma unroll
                for (int r = 0; r < 4; r++) {
                    const float pre = acc[tt][ht][r] + b1v;
                    const float ge  = 0.5f * pre * (1.0f + erff(pre * 0.70710678118654752f));
                    spart[tt*4 + r] += ge * w2v;
                }
        }
    }
#pragma unroll
    for (int i = 0; i < 16; i++) {
        float s = spart[i];
        s += __shfl_xor(s, 1, 64);
        s += __shfl_xor(s, 2, 64);
        s += __shfl_xor(s, 4, 64);
        s += __shfl_xor(s, 8, 64);
        spart[i] = s;
    }
    if (cn == 0) {
#pragma unroll
        for (int tt = 0; tt < 4; tt++)
#pragma unroll
            for (int r = 0; r < 4; r++)
                sred[wh][wt*64 + tt*16 + cq*4 + r] = spart[tt*4 + r];
    }
    __syncthreads();
    if (tid < TM) {
        scores[token0 + tid] = sred[0][tid] + sred[1][tid] + sred[2][tid] + sred[3][tid] + b2v[0];
    }
}

// ---------------------------------------------------------------------------
// Kernel TG: entmax1.5 tau (fp64 bisection) + Kumaraswamy gate, fused.
// One 1024-thread block per batch row. tau is block-uniform in registers.
// ---------------------------------------------------------------------------
static __device__ __forceinline__ double softplus_d(double x) {
    return (x > 30.0) ? x : log1p(exp(x));
}

__global__ __launch_bounds__(1024) void k_taugate(
    const float* __restrict__ scores, const float* __restrict__ attn,
    const float* __restrict__ u, float* __restrict__ out)
{
    const int b    = blockIdx.x;
    const int tid  = threadIdx.x;
    const int lane = tid & 63;
    const int wid  = tid >> 6;

    __shared__ double redd[2][16];
    __shared__ float  redf[16];
    __shared__ float  bcf;

    float vv[4], at[4], sm[4];
#pragma unroll
    for (int j = 0; j < 4; j++) {
        const int i = tid + 1024 * j;
        at[j] = attn[b * NS + i];
        const float s = scores[b * NS + i];
        sm[j] = (at[j] == 0.0f) ? -1e9f : s;
        vv[j] = sm[j] * 0.5f;
    }

    float mx = fmaxf(fmaxf(vv[0], vv[1]), fmaxf(vv[2], vv[3]));
#pragma unroll
    for (int m = 32; m; m >>= 1) mx = fmaxf(mx, __shfl_xor(mx, m, 64));
    if (lane == 0) redf[wid] = mx;
    __syncthreads();
    if (tid == 0) {
        float t = redf[0];
        for (int i = 1; i < 16; i++) t = fmaxf(t, redf[i]);
        bcf = t;
    }
    __syncthreads();
    const double mxd = (double)bcf;

    double d[4];
#pragma unroll
    for (int j = 0; j < 4; j++) d[j] = (double)vv[j] - mxd;

    double lo = -1.0, hi = 0.0;
    for (int it = 0; it < 44; it++) {
        const double mid = 0.5 * (lo + hi);
        double s = 0.0;
#pragma unroll
        for (int j = 0; j < 4; j++) {
            const double t = d[j] - mid;
            if (t > 0.0) s += t * t;
        }
#pragma unroll
        for (int m = 32; m; m >>= 1) s += __shfl_xor(s, m, 64);
        const int p = it & 1;
        if (lane == 0) redd[p][wid] = s;
        __syncthreads();
        double tot = 0.0;
#pragma unroll
        for (int i = 0; i < 16; i++) tot += redd[p][i];
        if (tot >= 1.0) lo = mid; else hi = mid;   // uniform across block
    }
    const double tau = lo;

    if (b == 0 && tid == 0) out[2 * NTOK] = 0.0f;  // reg

#pragma unroll
    for (int j = 0; j < 4; j++) {
        const int i = tid + 1024 * j;
        const double t  = d[j] - tau;
        const double zz = (t > 0.0) ? t * t : 0.0;
        const float  z  = (float)zz * at[j];

        const double eff  = (double)sm[j] + 2.0 * (2.0 * (double)z - 1.0);
        const double sp_p = softplus_d(eff)  + 1e-6;
        const double sp_n = softplus_d(-eff) + 1e-6;
        const double uc   = fmin(fmax((double)u[b * NS + i], 1e-6), 1.0 - 1e-6);
        const double xk   = pow(1.0 - pow(1.0 - uc, 1.0 / sp_n), 1.0 / sp_p);
        const double y    = -0.1 + 1.2 * xk;
        const double ycl  = fmin(fmax(y, 0.0), 1.0);
        float h = (ycl > 0.5) ? 1.0f : 0.0f;
        h *= at[j];
        const float g = (h - z) + z;

        out[b * NS + i]        = z;
        out[NTOK + b * NS + i] = g;
    }
}

// ---------------------------------------------------------------------------
extern "C" void kernel_launch(void* const* d_in, const int* in_sizes, int n_in,
                              void* d_out, int out_size, void* d_ws, size_t ws_size,
                              hipStream_t stream)
{
    const float* emb  = (const float*)d_in[0];
    const float* attn = (const float*)d_in[1];
    const float* u    = (const float*)d_in[2];
    const float* ln_g = (const float*)d_in[3];
    const float* ln_b = (const float*)d_in[4];
    const float* w1   = (const float*)d_in[5];
    const float* b1   = (const float*)d_in[6];
    const float* w2   = (const float*)d_in[7];
    const float* b2   = (const float*)d_in[8];
    float* out = (float*)d_out;

    float*  wsf    = (float*)d_ws;
    float*  scores = wsf;                       // NTOK
    float*  mu     = wsf + NTOK;                // NTOK
    float*  rs     = wsf + 2 * NTOK;            // NTOK
    bf16_t* w1hB   = (bf16_t*)(wsf + 3 * NTOK); // NH*ND bf16 (blocked)
    bf16_t* w1lB   = w1hB + (size_t)NH * ND;

    hipLaunchKernelGGL(k_lnstats, dim3(NTOK / 4), dim3(256), 0, stream,
                       emb, attn, mu, rs);
    hipLaunchKernelGGL(k_wprep, dim3((NKC * 64 * 64) / 256), dim3(256), 0, stream,
                       w1, w1hB, w1lB);
    hipLaunchKernelGGL(k_scorer, dim3(NTOK / TM), dim3(512), 0, stream,
                       emb, attn, ln_g, ln_b, w1hB, w1lB, b1, w2, b2, mu, rs, scores);
    hipLaunchKernelGGL(k_taugate, dim3(NB), dim3(1024), 0, stream,
                       scores, attn, u, out);
}